// Round 18
// baseline (145.546 us; speedup 1.0000x reference)
//
#include <hip/hip_runtime.h>
#include <hip/hip_bf16.h>

#define C_  19
#define D_  512
#define H_  4
#define DH_ 128
#define NROW 65536
#define CHP_ 96

typedef float f32x4 __attribute__((ext_vector_type(4)));
typedef short bf16x8 __attribute__((ext_vector_type(8)));
typedef unsigned short ushort4v __attribute__((ext_vector_type(4)));

__device__ __forceinline__ unsigned short f2bf(float f) {
  union { __hip_bfloat16 h; unsigned short s; } u;
  u.h = __float2bfloat16(f);
  return u.s;
}
__device__ __forceinline__ float bf2f(unsigned short h) {
  return __uint_as_float(((unsigned int)h) << 16);
}
__device__ __forceinline__ bf16x8 ld_cvt8(const float* p) {
  f32x4 v0 = *(const f32x4*)p;
  f32x4 v1 = *(const f32x4*)(p + 4);
  bf16x8 a;
  a[0]=(short)f2bf(v0[0]); a[1]=(short)f2bf(v0[1]);
  a[2]=(short)f2bf(v0[2]); a[3]=(short)f2bf(v0[3]);
  a[4]=(short)f2bf(v1[0]); a[5]=(short)f2bf(v1[1]);
  a[6]=(short)f2bf(v1[2]); a[7]=(short)f2bf(v1[3]);
  return a;
}

// ---- prep (r13-verbatim): K/V in-block, Mtf/Utf frag-order, bo at p=80 ----
__global__ __launch_bounds__(512) void prep(
    const float* __restrict__ ce,
    const float* __restrict__ Wq, const float* __restrict__ bq,
    const float* __restrict__ Wk, const float* __restrict__ bk,
    const float* __restrict__ Wv, const float* __restrict__ bv,
    const float* __restrict__ Wo, const float* __restrict__ bo,
    unsigned short* __restrict__ Mtf, unsigned short* __restrict__ Utf,
    float* __restrict__ s0g)
{
  __shared__ float KV[2][DH_];
  __shared__ float KVp[512];

  const int p = blockIdx.x;   // 0..95
  const int m = threadIdx.x;  // 0..511
  const int mt_off = (p>>4)*8192 + (m>>5)*512 + ((((m>>3)&3)<<4) + (p&15))*8 + (m&7);
  const int ut_off = ((m>>4)*3 + (p>>5))*512 + ((((p>>3)&3)<<4) + (m&15))*8 + (p&7);
  const int c = p >> 2, h = p & 3;

  if (c >= C_) {   // dead slots; p==80 carries bo (Wa col 80 is 1.0)
    if (p < 80) { Mtf[mt_off] = 0; if (m == 0) s0g[p] = 0.f; }
    Utf[ut_off] = (p == 80) ? f2bf(bo[m]) : (unsigned short)0;
    return;
  }

  {
    const int which = m >> 8;            // 0:K 1:V
    const int dh    = (m >> 1) & 127;
    const int half  = m & 1;
    const float* w = (which ? Wv : Wk) + (size_t)(h*DH_ + dh)*D_ + half*256;
    const float* e = ce + (size_t)c*D_ + half*256;
    float acc = 0.f;
    #pragma unroll 8
    for (int d = 0; d < 256; ++d) acc = fmaf(e[d], w[d], acc);
    KVp[m] = acc;
  }
  __syncthreads();
  if (m < 256) {
    const int which = m >> 7, dh = m & 127;
    KV[which][dh] = KVp[2*m] + KVp[2*m+1] + (which ? bv : bk)[h*DH_ + dh];
  }
  __syncthreads();

  const float rs128 = 0.08838834764831843f;  // 1/sqrt(128)
  float macc = 0.f;
  #pragma unroll 4
  for (int dh = 0; dh < DH_; ++dh)
    macc = fmaf(Wq[(size_t)(h*DH_+dh)*D_ + m], KV[0][dh], macc);
  Mtf[mt_off] = f2bf(macc * rs128);

  float uacc = 0.f;
  const float* wor = Wo + (size_t)m*D_ + h*DH_;
  #pragma unroll 4
  for (int dh = 0; dh < DH_; ++dh)
    uacc = fmaf(wor[dh], KV[1][dh], uacc);
  Utf[ut_off] = f2bf(uacc);

  if (m == 0) {
    float sa = 0.f;
    for (int dh = 0; dh < DH_; ++dh) sa = fmaf(bq[h*DH_+dh], KV[0][dh], sa);
    s0g[p] = sa * rs128;
  }
}

// ---- fused64 v3: ZERO barriers; swapped phase-3 (lane owns one row) --------
// Each wave self-contained: stages its 16 rows, scores+softmax them, and the
// swapped out-GEMM D^T layout puts lane on row wrow+llo with 4-consecutive
// cols -> f32x4 epilogue, wave-local LN.
__global__ __launch_bounds__(256) void fused64(
    const float* __restrict__ x,
    const unsigned short* __restrict__ Mtf,  // frag-ordered [5][16][64][8]
    const unsigned short* __restrict__ Utf,  // frag-ordered [32][3][64][8]
    const float* __restrict__ s0g,           // [80] permuted
    const float* __restrict__ gamma, const float* __restrict__ beta,
    float* __restrict__ out)
{
  __shared__ __attribute__((aligned(16))) unsigned short Xbf[64*512]; // 64KB swizzled
  __shared__ __attribute__((aligned(16))) unsigned short WaL[64][104];

  const int t    = threadIdx.x;
  const int wave = t >> 6;
  const int lane = t & 63;
  const int lhi  = lane >> 4;
  const int llo  = lane & 15;
  const int row0 = blockIdx.x * 64;
  const int wrow = wave * 16;     // this wave's local row base

  // ---- phase 0: stage this wave's 16 rows -> Xbf (bf16, swizzled) ----
  {
    #pragma unroll
    for (int j = 0; j < 16; ++j) {
      bf16x8 a = ld_cvt8(x + (size_t)(row0 + wrow + j)*D_ + lane*8);
      int byteoff = (wrow + j)*1024 + ((lane*16) ^ ((j & 7) << 4));
      *(bf16x8*)((char*)Xbf + byteoff) = a;
    }
  }
  asm volatile("s_waitcnt lgkmcnt(0)" ::: "memory");
  __builtin_amdgcn_sched_barrier(0);

  // ---- phase 1: S-GEMM, ks-outer, 5 accs, A from LDS (r17-verbatim) ----
  {
    const char* xb = (const char*)Xbf + (wrow + llo)*1024;
    const int swz = (llo & 7) << 4;
    f32x4 acc0 = (f32x4){0,0,0,0}, acc1 = acc0, acc2 = acc0, acc3 = acc0, acc4 = acc0;
    #pragma unroll
    for (int ks = 0; ks < 16; ++ks) {
      bf16x8 a = *(const bf16x8*)(xb + ((ks*64 + lhi*16) ^ swz));
      acc0 = __builtin_amdgcn_mfma_f32_16x16x32_bf16(a, *(const bf16x8*)(Mtf + 0*8192 + ks*512 + lane*8), acc0, 0, 0, 0);
      acc1 = __builtin_amdgcn_mfma_f32_16x16x32_bf16(a, *(const bf16x8*)(Mtf + 1*8192 + ks*512 + lane*8), acc1, 0, 0, 0);
      acc2 = __builtin_amdgcn_mfma_f32_16x16x32_bf16(a, *(const bf16x8*)(Mtf + 2*8192 + ks*512 + lane*8), acc2, 0, 0, 0);
      acc3 = __builtin_amdgcn_mfma_f32_16x16x32_bf16(a, *(const bf16x8*)(Mtf + 3*8192 + ks*512 + lane*8), acc3, 0, 0, 0);
      acc4 = __builtin_amdgcn_mfma_f32_16x16x32_bf16(a, *(const bf16x8*)(Mtf + 4*8192 + ks*512 + lane*8), acc4, 0, 0, 0);
    }
    // in-register softmax over p (h = llo&3 lane-invariant under xor 4,8)
    const bool dead = (llo >= 12);   // slot p=64+llo: c = 16+(llo>>2) == 19
    float s0v0 = s0g[llo], s0v1 = s0g[16+llo], s0v2 = s0g[32+llo],
          s0v3 = s0g[48+llo], s0v4 = s0g[64+llo];
    #pragma unroll
    for (int r = 0; r < 4; ++r) {
      float v0 = acc0[r] + s0v0;
      float v1 = acc1[r] + s0v1;
      float v2 = acc2[r] + s0v2;
      float v3 = acc3[r] + s0v3;
      float v4 = dead ? -1e30f : (acc4[r] + s0v4);
      float mx = fmaxf(fmaxf(fmaxf(v0, v1), fmaxf(v2, v3)), v4);
      mx = fmaxf(mx, __shfl_xor(mx, 4, 64));
      mx = fmaxf(mx, __shfl_xor(mx, 8, 64));
      float e0 = __expf(v0 - mx), e1 = __expf(v1 - mx), e2 = __expf(v2 - mx),
            e3 = __expf(v3 - mx), e4 = dead ? 0.f : __expf(v4 - mx);
      float sm = e0 + e1 + e2 + e3 + e4;
      sm += __shfl_xor(sm, 4, 64);
      sm += __shfl_xor(sm, 8, 64);
      float inv = 1.f / sm;
      int lr = wrow + lhi*4 + r;
      WaL[lr][     llo] = f2bf(e0 * inv);
      WaL[lr][16 + llo] = f2bf(e1 * inv);
      WaL[lr][32 + llo] = f2bf(e2 * inv);
      WaL[lr][48 + llo] = f2bf(e3 * inv);
      WaL[lr][64 + llo] = f2bf(e4 * inv);
    }
    // pad cols 80..95: col 80 = 1.0 (bo slot), rest 0
    {
      int prow = wrow + lhi*4 + (llo & 3);
      int cj   = llo >> 2;
      WaL[prow][80 + cj*4 + 0] = (cj == 0) ? (unsigned short)0x3F80 : (unsigned short)0;
      WaL[prow][80 + cj*4 + 1] = 0;
      WaL[prow][80 + cj*4 + 2] = 0;
      WaL[prow][80 + cj*4 + 3] = 0;
    }
  }
  asm volatile("s_waitcnt lgkmcnt(0)" ::: "memory");
  __builtin_amdgcn_sched_barrier(0);

  // ---- phase 3 SWAPPED: out[m][n], lane owns row m = wrow+llo,
  //      cols n = tile*16 + lhi*4 + r (4 consecutive). Two 256-col passes. ----
  const int myrow = wrow + llo;
  const char* xrow = (const char*)Xbf + myrow*1024;
  const int rswz = (myrow & 7) << 4;
  float s = 0.f, q = 0.f;
  unsigned int pk[32];

  f32x4 oa[16];
  // pass A: tiles 0..15 (cols 0..255) -> bf16-packed
  #pragma unroll
  for (int i = 0; i < 16; ++i) oa[i] = (f32x4){0,0,0,0};
  #pragma unroll
  for (int ks = 0; ks < 3; ++ks) {
    bf16x8 wb = *(const bf16x8*)&WaL[myrow][ks*32 + lhi*8];
    #pragma unroll
    for (int tl = 0; tl < 16; ++tl) {
      bf16x8 ua = *(const bf16x8*)(Utf + (size_t)(tl*3 + ks)*512 + lane*8);
      oa[tl] = __builtin_amdgcn_mfma_f32_16x16x32_bf16(ua, wb, oa[tl], 0, 0, 0);
    }
  }
  #pragma unroll
  for (int tl = 0; tl < 16; ++tl) {
    // residual: 4 consecutive bf16 of this lane's row (8B LDS read)
    ushort4v xr = *(const ushort4v*)(xrow + ((tl*32 + lhi*8) ^ rswz));
    #pragma unroll
    for (int r = 0; r < 4; ++r) {
      float val = oa[tl][r] + bf2f(xr[r]);
      oa[tl][r] = val;
      s += val;
      q = fmaf(val, val, q);
    }
    pk[tl*2    ] = (unsigned int)f2bf(oa[tl][0]) | ((unsigned int)f2bf(oa[tl][1]) << 16);
    pk[tl*2 + 1] = (unsigned int)f2bf(oa[tl][2]) | ((unsigned int)f2bf(oa[tl][3]) << 16);
  }

  // pass B: tiles 16..31 (cols 256..511), f32 kept
  #pragma unroll
  for (int i = 0; i < 16; ++i) oa[i] = (f32x4){0,0,0,0};
  #pragma unroll
  for (int ks = 0; ks < 3; ++ks) {
    bf16x8 wb = *(const bf16x8*)&WaL[myrow][ks*32 + lhi*8];
    #pragma unroll
    for (int tl = 0; tl < 16; ++tl) {
      bf16x8 ua = *(const bf16x8*)(Utf + (size_t)((16 + tl)*3 + ks)*512 + lane*8);
      oa[tl] = __builtin_amdgcn_mfma_f32_16x16x32_bf16(ua, wb, oa[tl], 0, 0, 0);
    }
  }
  #pragma unroll
  for (int tl = 0; tl < 16; ++tl) {
    ushort4v xr = *(const ushort4v*)(xrow + (((16 + tl)*32 + lhi*8) ^ rswz));
    #pragma unroll
    for (int r = 0; r < 4; ++r) {
      float val = oa[tl][r] + bf2f(xr[r]);
      oa[tl][r] = val;
      s += val;
      q = fmaf(val, val, q);
    }
  }

  // ---- wave-local LN stats: reduce over lhi (lanes llo, llo+16, +32, +48) ----
  s += __shfl_xor(s, 16, 64);
  s += __shfl_xor(s, 32, 64);
  q += __shfl_xor(q, 16, 64);
  q += __shfl_xor(q, 32, 64);
  float mu   = s * (1.f/(float)D_);
  float var  = q * (1.f/(float)D_) - mu*mu;
  float rstd = rsqrtf(var + 1e-5f);

  // ---- stores: one ordered sweep, f32x4, row-contiguous in time ----
  float* orow = out + (size_t)(row0 + myrow)*D_;
  #pragma unroll
  for (int tl = 0; tl < 16; ++tl) {
    int n0 = tl*16 + lhi*4;
    f32x4 gv = *(const f32x4*)(gamma + n0);
    f32x4 bv = *(const f32x4*)(beta + n0);
    float v0 = bf2f((unsigned short)(pk[tl*2] & 0xFFFF));
    float v1 = bf2f((unsigned short)(pk[tl*2] >> 16));
    float v2 = bf2f((unsigned short)(pk[tl*2+1] & 0xFFFF));
    float v3 = bf2f((unsigned short)(pk[tl*2+1] >> 16));
    f32x4 o;
    o[0] = (v0 - mu) * rstd * gv[0] + bv[0];
    o[1] = (v1 - mu) * rstd * gv[1] + bv[1];
    o[2] = (v2 - mu) * rstd * gv[2] + bv[2];
    o[3] = (v3 - mu) * rstd * gv[3] + bv[3];
    *(f32x4*)(orow + n0) = o;
  }
  #pragma unroll
  for (int tl = 0; tl < 16; ++tl) {
    int n0 = 256 + tl*16 + lhi*4;
    f32x4 gv = *(const f32x4*)(gamma + n0);
    f32x4 bv = *(const f32x4*)(beta + n0);
    f32x4 val = oa[tl];
    f32x4 o;
    o[0] = (val[0] - mu) * rstd * gv[0] + bv[0];
    o[1] = (val[1] - mu) * rstd * gv[1] + bv[1];
    o[2] = (val[2] - mu) * rstd * gv[2] + bv[2];
    o[3] = (val[3] - mu) * rstd * gv[3] + bv[3];
    *(f32x4*)(orow + n0) = o;
  }
}

extern "C" void kernel_launch(void* const* d_in, const int* in_sizes, int n_in,
                              void* d_out, int out_size, void* d_ws, size_t ws_size,
                              hipStream_t stream) {
  const float* x     = (const float*)d_in[0];
  const float* ce    = (const float*)d_in[1];
  const float* Wq    = (const float*)d_in[2];
  const float* bq    = (const float*)d_in[3];
  const float* Wk    = (const float*)d_in[4];
  const float* bk    = (const float*)d_in[5];
  const float* Wv    = (const float*)d_in[6];
  const float* bv    = (const float*)d_in[7];
  const float* Wo    = (const float*)d_in[8];
  const float* bo    = (const float*)d_in[9];
  const float* gamma = (const float*)d_in[10];
  const float* beta  = (const float*)d_in[11];
  float* out = (float*)d_out;

  char* ws = (char*)d_ws;
  unsigned short* Mtf = (unsigned short*)(ws);           // 80*512*2 = 81920
  unsigned short* Utf = (unsigned short*)(ws + 81920);   // 512*96*2 = 98304
  float* s0g          = (float*)(ws + 180224);           // 320

  prep<<<CHP_, 512, 0, stream>>>(ce, Wq, bq, Wk, bk, Wv, bv, Wo, bo,
                                 Mtf, Utf, s0g);
  fused64<<<NROW/64, 256, 0, stream>>>(x, Mtf, Utf, s0g, gamma, beta, out);
}

// Round 19
// 134.216 us; speedup vs baseline: 1.0844x; 1.0844x over previous
//
#include <hip/hip_runtime.h>
#include <hip/hip_bf16.h>

#define C_  19
#define D_  512
#define H_  4
#define DH_ 128
#define NROW 65536
#define CHP_ 96

typedef float f32x4 __attribute__((ext_vector_type(4)));
typedef short bf16x8 __attribute__((ext_vector_type(8)));

__device__ __forceinline__ unsigned short f2bf(float f) {
  union { __hip_bfloat16 h; unsigned short s; } u;
  u.h = __float2bfloat16(f);
  return u.s;
}
__device__ __forceinline__ float bf2f(unsigned short h) {
  return __uint_as_float(((unsigned int)h) << 16);
}
__device__ __forceinline__ bf16x8 ld_cvt8(const float* p) {
  f32x4 v0 = *(const f32x4*)p;
  f32x4 v1 = *(const f32x4*)(p + 4);
  bf16x8 a;
  a[0]=(short)f2bf(v0[0]); a[1]=(short)f2bf(v0[1]);
  a[2]=(short)f2bf(v0[2]); a[3]=(short)f2bf(v0[3]);
  a[4]=(short)f2bf(v1[0]); a[5]=(short)f2bf(v1[1]);
  a[6]=(short)f2bf(v1[2]); a[7]=(short)f2bf(v1[3]);
  return a;
}

// ---- prep_kv (r5-prep1 verbatim): K/V = ce @ W^T + b (f32) ---------------
__global__ __launch_bounds__(256) void prep_kv(
    const float* __restrict__ ce,
    const float* __restrict__ Wk, const float* __restrict__ bk,
    const float* __restrict__ Wv, const float* __restrict__ bv,
    float* __restrict__ Kg, float* __restrict__ Vg)
{
  int g = blockIdx.x * 256 + threadIdx.x;
  if (g >= 2*C_*D_) return;
  int which = (g >= C_*D_) ? 1 : 0;
  int idx = which ? (g - C_*D_) : g;
  int c = idx >> 9;
  int n = idx & (D_-1);
  const float* w = (which ? Wv : Wk) + (size_t)n * D_;
  const float* e = ce + (size_t)c * D_;
  float s = 0.f;
  #pragma unroll 8
  for (int d = 0; d < D_; ++d) s = fmaf(e[d], w[d], s);
  s += (which ? bv : bk)[n];
  if (which) Vg[idx] = s; else Kg[idx] = s;
}

// ---- prep_mu: Mtf/Utf frag-order + s0, reading Kg/Vg; 192 blocks ----------
// p = bid>>1, m = (bid&1)*256 + t. Layouts identical to the proven merged prep.
__global__ __launch_bounds__(256) void prep_mu(
    const float* __restrict__ Wq, const float* __restrict__ bq,
    const float* __restrict__ Wo, const float* __restrict__ bo,
    const float* __restrict__ Kg, const float* __restrict__ Vg,
    unsigned short* __restrict__ Mtf, unsigned short* __restrict__ Utf,
    float* __restrict__ s0g)
{
  const int p = blockIdx.x >> 1;               // 0..95
  const int m = (blockIdx.x & 1)*256 + threadIdx.x;  // 0..511
  const int mt_off = (p>>4)*8192 + (m>>5)*512 + ((((m>>3)&3)<<4) + (p&15))*8 + (m&7);
  const int ut_off = ((m>>4)*3 + (p>>5))*512 + ((((p>>3)&3)<<4) + (m&15))*8 + (p&7);
  const int c = p >> 2, h = p & 3;

  if (c >= C_) {   // dead slots; p==80 carries bo (Wa col 80 is 1.0)
    if (p < 80) { Mtf[mt_off] = 0; if (m == 0) s0g[p] = 0.f; }
    Utf[ut_off] = (p == 80) ? f2bf(bo[m]) : (unsigned short)0;
    return;
  }

  const float rs128 = 0.08838834764831843f;  // 1/sqrt(128)
  const float* Kr = Kg + c*D_ + h*DH_;
  const float* Vr = Vg + c*D_ + h*DH_;

  float macc = 0.f;
  #pragma unroll 4
  for (int dh = 0; dh < DH_; ++dh)
    macc = fmaf(Wq[(size_t)(h*DH_+dh)*D_ + m], Kr[dh], macc);
  Mtf[mt_off] = f2bf(macc * rs128);

  float uacc = 0.f;
  const float* wor = Wo + (size_t)m*D_ + h*DH_;
  #pragma unroll 4
  for (int dh = 0; dh < DH_; ++dh)
    uacc = fmaf(wor[dh], Vr[dh], uacc);
  Utf[ut_off] = f2bf(uacc);

  if (m == 0) {
    float sa = 0.f;
    for (int dh = 0; dh < DH_; ++dh) sa = fmaf(bq[h*DH_+dh], Kr[dh], sa);
    s0g[p] = sa * rs128;
  }
}

// ---- fused64 (r17-VERBATIM): 64 rows/block, 4 waves, 3 barriers -----------
__global__ __launch_bounds__(256) void fused64(
    const float* __restrict__ x,
    const unsigned short* __restrict__ Mtf,  // frag-ordered [5][16][64][8]
    const unsigned short* __restrict__ Utf,  // frag-ordered [32][3][64][8]
    const float* __restrict__ s0g,           // [80] permuted
    const float* __restrict__ gamma, const float* __restrict__ beta,
    float* __restrict__ out)
{
  __shared__ __attribute__((aligned(16))) unsigned short Xbf[64*512]; // 64KB swizzled
  __shared__ __attribute__((aligned(16))) unsigned short WaL[64][104];
  __shared__ float rs_[64][2], rq_[64][2];

  const int t    = threadIdx.x;
  const int wave = t >> 6;
  const int lane = t & 63;
  const int lhi  = lane >> 4;
  const int llo  = lane & 15;
  const int row0 = blockIdx.x * 64;
  const int wrow = wave * 16;     // this wave's local row base

  // ---- phase 0: stage this wave's 16 rows -> Xbf (bf16, swizzled) ----
  {
    #pragma unroll
    for (int j = 0; j < 16; ++j) {
      bf16x8 a = ld_cvt8(x + (size_t)(row0 + wrow + j)*D_ + lane*8);
      int byteoff = (wrow + j)*1024 + ((lane*16) ^ ((j & 7) << 4));
      *(bf16x8*)((char*)Xbf + byteoff) = a;
    }
  }
  // wave-local fence: this wave's LDS writes -> this wave's phase-1 reads
  asm volatile("s_waitcnt lgkmcnt(0)" ::: "memory");
  __builtin_amdgcn_sched_barrier(0);

  // ---- phase 1: S-GEMM, ks-outer, 5 accs, A from LDS ----
  {
    const char* xb = (const char*)Xbf + (wrow + llo)*1024;
    const int swz = (llo & 7) << 4;
    f32x4 acc0 = (f32x4){0,0,0,0}, acc1 = acc0, acc2 = acc0, acc3 = acc0, acc4 = acc0;
    #pragma unroll
    for (int ks = 0; ks < 16; ++ks) {
      bf16x8 a = *(const bf16x8*)(xb + ((ks*64 + lhi*16) ^ swz));
      acc0 = __builtin_amdgcn_mfma_f32_16x16x32_bf16(a, *(const bf16x8*)(Mtf + 0*8192 + ks*512 + lane*8), acc0, 0, 0, 0);
      acc1 = __builtin_amdgcn_mfma_f32_16x16x32_bf16(a, *(const bf16x8*)(Mtf + 1*8192 + ks*512 + lane*8), acc1, 0, 0, 0);
      acc2 = __builtin_amdgcn_mfma_f32_16x16x32_bf16(a, *(const bf16x8*)(Mtf + 2*8192 + ks*512 + lane*8), acc2, 0, 0, 0);
      acc3 = __builtin_amdgcn_mfma_f32_16x16x32_bf16(a, *(const bf16x8*)(Mtf + 3*8192 + ks*512 + lane*8), acc3, 0, 0, 0);
      acc4 = __builtin_amdgcn_mfma_f32_16x16x32_bf16(a, *(const bf16x8*)(Mtf + 4*8192 + ks*512 + lane*8), acc4, 0, 0, 0);
    }
    // in-register softmax over p (h = llo&3 lane-invariant under xor 4,8)
    const bool dead = (llo >= 12);   // slot p=64+llo: c = 16+(llo>>2) == 19
    float s0v0 = s0g[llo], s0v1 = s0g[16+llo], s0v2 = s0g[32+llo],
          s0v3 = s0g[48+llo], s0v4 = s0g[64+llo];
    #pragma unroll
    for (int r = 0; r < 4; ++r) {
      float v0 = acc0[r] + s0v0;
      float v1 = acc1[r] + s0v1;
      float v2 = acc2[r] + s0v2;
      float v3 = acc3[r] + s0v3;
      float v4 = dead ? -1e30f : (acc4[r] + s0v4);
      float mx = fmaxf(fmaxf(fmaxf(v0, v1), fmaxf(v2, v3)), v4);
      mx = fmaxf(mx, __shfl_xor(mx, 4, 64));
      mx = fmaxf(mx, __shfl_xor(mx, 8, 64));
      float e0 = __expf(v0 - mx), e1 = __expf(v1 - mx), e2 = __expf(v2 - mx),
            e3 = __expf(v3 - mx), e4 = dead ? 0.f : __expf(v4 - mx);
      float sm = e0 + e1 + e2 + e3 + e4;
      sm += __shfl_xor(sm, 4, 64);
      sm += __shfl_xor(sm, 8, 64);
      float inv = 1.f / sm;
      int lr = wrow + lhi*4 + r;
      WaL[lr][     llo] = f2bf(e0 * inv);
      WaL[lr][16 + llo] = f2bf(e1 * inv);
      WaL[lr][32 + llo] = f2bf(e2 * inv);
      WaL[lr][48 + llo] = f2bf(e3 * inv);
      WaL[lr][64 + llo] = f2bf(e4 * inv);
    }
    // pad cols 80..95: col 80 = 1.0 (bo slot), rest 0 (r13-proven join)
    {
      int prow = wrow + lhi*4 + (llo & 3);
      int cj   = llo >> 2;
      WaL[prow][80 + cj*4 + 0] = (cj == 0) ? (unsigned short)0x3F80 : (unsigned short)0;
      WaL[prow][80 + cj*4 + 1] = 0;
      WaL[prow][80 + cj*4 + 2] = 0;
      WaL[prow][80 + cj*4 + 3] = 0;
    }
  }
  __syncthreads();   // BAR1: WaL + all Xbf staging visible block-wide

  // ---- phases 3+4, per 32-row half (bo via WaL col 80) ----
  const int rg = wave >> 1;
  const int cs = wave & 1;
  #pragma unroll
  for (int ha = 0; ha < 2; ++ha) {
    const int hrow = ha * 32;              // local row base of this half
    f32x4 oacc[16];
    #pragma unroll
    for (int i = 0; i < 16; ++i) oacc[i] = (f32x4){0.f,0.f,0.f,0.f};
    #pragma unroll
    for (int ks = 0; ks < 3; ++ks) {
      bf16x8 a = *(const bf16x8*)&WaL[hrow + rg*16 + llo][ks*32 + lhi*8];
      #pragma unroll
      for (int tile = 0; tile < 16; ++tile) {
        int ntile = cs*16 + tile;
        bf16x8 b = *(const bf16x8*)(Utf + (size_t)(ntile*3 + ks)*512 + lane*8);
        oacc[tile] = __builtin_amdgcn_mfma_f32_16x16x32_bf16(a, b, oacc[tile], 0, 0, 0);
      }
    }
    // oacc[tile][r] = (attn+bo)[local m = hrow+rg*16+lhi*4+r][n = cs*256+tile*16+llo]

    // epilogue: +x residual (LDS bf16), LN stats, store
    float s[4] = {0,0,0,0}, q[4] = {0,0,0,0};
    #pragma unroll
    for (int tile = 0; tile < 16; ++tile) {
      int n = cs*256 + tile*16 + llo;
      #pragma unroll
      for (int r = 0; r < 4; ++r) {
        int m = hrow + rg*16 + lhi*4 + r;
        float xres = bf2f(*(const unsigned short*)
            ((const char*)Xbf + m*1024 + ((n*2) ^ ((m & 7) << 4))));
        float val = oacc[tile][r] + xres;
        oacc[tile][r] = val;
        s[r] += val;
        q[r] = fmaf(val, val, q[r]);
      }
    }
    #pragma unroll
    for (int r = 0; r < 4; ++r) {
      #pragma unroll
      for (int off = 1; off < 16; off <<= 1) {
        s[r] += __shfl_xor(s[r], off, 64);
        q[r] += __shfl_xor(q[r], off, 64);
      }
    }
    if (llo == 0) {
      #pragma unroll
      for (int r = 0; r < 4; ++r) {
        rs_[hrow + rg*16 + lhi*4 + r][cs] = s[r];
        rq_[hrow + rg*16 + lhi*4 + r][cs] = q[r];
      }
    }
    __syncthreads();   // BAR2 / BAR3: stats for this half ready
    float mu_r[4], rstd_r[4];
    #pragma unroll
    for (int r = 0; r < 4; ++r) {
      int m = hrow + rg*16 + lhi*4 + r;
      float sum = rs_[m][0] + rs_[m][1];
      float sq  = rq_[m][0] + rq_[m][1];
      float mu  = sum * (1.f/(float)D_);
      float var = sq * (1.f/(float)D_) - mu*mu;
      mu_r[r]   = mu;
      rstd_r[r] = rsqrtf(var + 1e-5f);
    }
    #pragma unroll
    for (int tile = 0; tile < 16; ++tile) {
      int n = cs*256 + tile*16 + llo;
      float g = gamma[n], bt = beta[n];
      #pragma unroll
      for (int r = 0; r < 4; ++r) {
        int m = hrow + rg*16 + lhi*4 + r;
        out[(size_t)(row0 + m)*D_ + n] = (oacc[tile][r] - mu_r[r]) * rstd_r[r] * g + bt;
      }
    }
  }
}

extern "C" void kernel_launch(void* const* d_in, const int* in_sizes, int n_in,
                              void* d_out, int out_size, void* d_ws, size_t ws_size,
                              hipStream_t stream) {
  const float* x     = (const float*)d_in[0];
  const float* ce    = (const float*)d_in[1];
  const float* Wq    = (const float*)d_in[2];
  const float* bq    = (const float*)d_in[3];
  const float* Wk    = (const float*)d_in[4];
  const float* bk    = (const float*)d_in[5];
  const float* Wv    = (const float*)d_in[6];
  const float* bv    = (const float*)d_in[7];
  const float* Wo    = (const float*)d_in[8];
  const float* bo    = (const float*)d_in[9];
  const float* gamma = (const float*)d_in[10];
  const float* beta  = (const float*)d_in[11];
  float* out = (float*)d_out;

  char* ws = (char*)d_ws;
  float* Kg           = (float*)(ws);                    // 38912
  float* Vg           = (float*)(ws + 40960);            // 38912
  unsigned short* Mtf = (unsigned short*)(ws + 81920);   // 80*512*2 = 81920
  unsigned short* Utf = (unsigned short*)(ws + 163840);  // 512*96*2 = 98304
  float* s0g          = (float*)(ws + 262144);           // 320

  prep_kv<<<(2*C_*D_ + 255)/256, 256, 0, stream>>>(ce, Wk, bk, Wv, bv, Kg, Vg);
  prep_mu<<<192, 256, 0, stream>>>(Wq, bq, Wo, bo, Kg, Vg, Mtf, Utf, s0g);
  fused64<<<NROW/64, 256, 0, stream>>>(x, Mtf, Utf, s0g, gamma, beta, out);
}

// Round 20
// 131.001 us; speedup vs baseline: 1.1110x; 1.0245x over previous
//
#include <hip/hip_runtime.h>
#include <hip/hip_bf16.h>

#define C_  19
#define D_  512
#define H_  4
#define DH_ 128
#define NROW 65536
#define CHP_ 96

typedef float f32x4 __attribute__((ext_vector_type(4)));
typedef short bf16x8 __attribute__((ext_vector_type(8)));

__device__ __forceinline__ unsigned short f2bf(float f) {
  union { __hip_bfloat16 h; unsigned short s; } u;
  u.h = __float2bfloat16(f);
  return u.s;
}
__device__ __forceinline__ float bf2f(unsigned short h) {
  return __uint_as_float(((unsigned int)h) << 16);
}
__device__ __forceinline__ bf16x8 ld_cvt8(const float* p) {
  f32x4 v0 = *(const f32x4*)p;
  f32x4 v1 = *(const f32x4*)(p + 4);
  bf16x8 a;
  a[0]=(short)f2bf(v0[0]); a[1]=(short)f2bf(v0[1]);
  a[2]=(short)f2bf(v0[2]); a[3]=(short)f2bf(v0[3]);
  a[4]=(short)f2bf(v1[0]); a[5]=(short)f2bf(v1[1]);
  a[6]=(short)f2bf(v1[2]); a[7]=(short)f2bf(v1[3]);
  return a;
}

// ---- prep (r13/r17-verbatim): K/V in-block, Mtf/Utf frag-order, bo at p=80 -
__global__ __launch_bounds__(512) void prep(
    const float* __restrict__ ce,
    const float* __restrict__ Wq, const float* __restrict__ bq,
    const float* __restrict__ Wk, const float* __restrict__ bk,
    const float* __restrict__ Wv, const float* __restrict__ bv,
    const float* __restrict__ Wo, const float* __restrict__ bo,
    unsigned short* __restrict__ Mtf, unsigned short* __restrict__ Utf,
    float* __restrict__ s0g)
{
  __shared__ float KV[2][DH_];
  __shared__ float KVp[512];

  const int p = blockIdx.x;   // 0..95
  const int m = threadIdx.x;  // 0..511
  const int mt_off = (p>>4)*8192 + (m>>5)*512 + ((((m>>3)&3)<<4) + (p&15))*8 + (m&7);
  const int ut_off = ((m>>4)*3 + (p>>5))*512 + ((((p>>3)&3)<<4) + (m&15))*8 + (p&7);
  const int c = p >> 2, h = p & 3;

  if (c >= C_) {   // dead slots; p==80 carries bo (Wa col 80 is 1.0)
    if (p < 80) { Mtf[mt_off] = 0; if (m == 0) s0g[p] = 0.f; }
    Utf[ut_off] = (p == 80) ? f2bf(bo[m]) : (unsigned short)0;
    return;
  }

  {
    const int which = m >> 8;            // 0:K 1:V
    const int dh    = (m >> 1) & 127;
    const int half  = m & 1;
    const float* w = (which ? Wv : Wk) + (size_t)(h*DH_ + dh)*D_ + half*256;
    const float* e = ce + (size_t)c*D_ + half*256;
    float acc = 0.f;
    #pragma unroll 8
    for (int d = 0; d < 256; ++d) acc = fmaf(e[d], w[d], acc);
    KVp[m] = acc;
  }
  __syncthreads();
  if (m < 256) {
    const int which = m >> 7, dh = m & 127;
    KV[which][dh] = KVp[2*m] + KVp[2*m+1] + (which ? bv : bk)[h*DH_ + dh];
  }
  __syncthreads();

  const float rs128 = 0.08838834764831843f;  // 1/sqrt(128)
  float macc = 0.f;
  #pragma unroll 4
  for (int dh = 0; dh < DH_; ++dh)
    macc = fmaf(Wq[(size_t)(h*DH_+dh)*D_ + m], KV[0][dh], macc);
  Mtf[mt_off] = f2bf(macc * rs128);

  float uacc = 0.f;
  const float* wor = Wo + (size_t)m*D_ + h*DH_;
  #pragma unroll 4
  for (int dh = 0; dh < DH_; ++dh)
    uacc = fmaf(wor[dh], KV[1][dh], uacc);
  Utf[ut_off] = f2bf(uacc);

  if (m == 0) {
    float sa = 0.f;
    for (int dh = 0; dh < DH_; ++dh) sa = fmaf(bq[h*DH_+dh], KV[0][dh], sa);
    s0g[p] = sa * rs128;
  }
}

// ---- fused64 (r17-verbatim): 64 rows/block, 4 waves, 3 barriers -----------
__global__ __launch_bounds__(256) void fused64(
    const float* __restrict__ x,
    const unsigned short* __restrict__ Mtf,  // frag-ordered [5][16][64][8]
    const unsigned short* __restrict__ Utf,  // frag-ordered [32][3][64][8]
    const float* __restrict__ s0g,           // [80] permuted
    const float* __restrict__ gamma, const float* __restrict__ beta,
    float* __restrict__ out)
{
  __shared__ __attribute__((aligned(16))) unsigned short Xbf[64*512]; // 64KB swizzled
  __shared__ __attribute__((aligned(16))) unsigned short WaL[64][104];
  __shared__ float rs_[64][2], rq_[64][2];

  const int t    = threadIdx.x;
  const int wave = t >> 6;
  const int lane = t & 63;
  const int lhi  = lane >> 4;
  const int llo  = lane & 15;
  const int row0 = blockIdx.x * 64;
  const int wrow = wave * 16;     // this wave's local row base

  // ---- phase 0: stage this wave's 16 rows -> Xbf (bf16, swizzled) ----
  {
    #pragma unroll
    for (int j = 0; j < 16; ++j) {
      bf16x8 a = ld_cvt8(x + (size_t)(row0 + wrow + j)*D_ + lane*8);
      int byteoff = (wrow + j)*1024 + ((lane*16) ^ ((j & 7) << 4));
      *(bf16x8*)((char*)Xbf + byteoff) = a;
    }
  }
  // wave-local fence: this wave's LDS writes -> this wave's phase-1 reads
  asm volatile("s_waitcnt lgkmcnt(0)" ::: "memory");
  __builtin_amdgcn_sched_barrier(0);

  // ---- phase 1: S-GEMM, ks-outer, 5 accs, A from LDS ----
  {
    const char* xb = (const char*)Xbf + (wrow + llo)*1024;
    const int swz = (llo & 7) << 4;
    f32x4 acc0 = (f32x4){0,0,0,0}, acc1 = acc0, acc2 = acc0, acc3 = acc0, acc4 = acc0;
    #pragma unroll
    for (int ks = 0; ks < 16; ++ks) {
      bf16x8 a = *(const bf16x8*)(xb + ((ks*64 + lhi*16) ^ swz));
      acc0 = __builtin_amdgcn_mfma_f32_16x16x32_bf16(a, *(const bf16x8*)(Mtf + 0*8192 + ks*512 + lane*8), acc0, 0, 0, 0);
      acc1 = __builtin_amdgcn_mfma_f32_16x16x32_bf16(a, *(const bf16x8*)(Mtf + 1*8192 + ks*512 + lane*8), acc1, 0, 0, 0);
      acc2 = __builtin_amdgcn_mfma_f32_16x16x32_bf16(a, *(const bf16x8*)(Mtf + 2*8192 + ks*512 + lane*8), acc2, 0, 0, 0);
      acc3 = __builtin_amdgcn_mfma_f32_16x16x32_bf16(a, *(const bf16x8*)(Mtf + 3*8192 + ks*512 + lane*8), acc3, 0, 0, 0);
      acc4 = __builtin_amdgcn_mfma_f32_16x16x32_bf16(a, *(const bf16x8*)(Mtf + 4*8192 + ks*512 + lane*8), acc4, 0, 0, 0);
    }
    // in-register softmax over p (h = llo&3 lane-invariant under xor 4,8)
    const bool dead = (llo >= 12);   // slot p=64+llo: c = 16+(llo>>2) == 19
    float s0v0 = s0g[llo], s0v1 = s0g[16+llo], s0v2 = s0g[32+llo],
          s0v3 = s0g[48+llo], s0v4 = s0g[64+llo];
    #pragma unroll
    for (int r = 0; r < 4; ++r) {
      float v0 = acc0[r] + s0v0;
      float v1 = acc1[r] + s0v1;
      float v2 = acc2[r] + s0v2;
      float v3 = acc3[r] + s0v3;
      float v4 = dead ? -1e30f : (acc4[r] + s0v4);
      float mx = fmaxf(fmaxf(fmaxf(v0, v1), fmaxf(v2, v3)), v4);
      mx = fmaxf(mx, __shfl_xor(mx, 4, 64));
      mx = fmaxf(mx, __shfl_xor(mx, 8, 64));
      float e0 = __expf(v0 - mx), e1 = __expf(v1 - mx), e2 = __expf(v2 - mx),
            e3 = __expf(v3 - mx), e4 = dead ? 0.f : __expf(v4 - mx);
      float sm = e0 + e1 + e2 + e3 + e4;
      sm += __shfl_xor(sm, 4, 64);
      sm += __shfl_xor(sm, 8, 64);
      float inv = 1.f / sm;
      int lr = wrow + lhi*4 + r;
      WaL[lr][     llo] = f2bf(e0 * inv);
      WaL[lr][16 + llo] = f2bf(e1 * inv);
      WaL[lr][32 + llo] = f2bf(e2 * inv);
      WaL[lr][48 + llo] = f2bf(e3 * inv);
      WaL[lr][64 + llo] = f2bf(e4 * inv);
    }
    // pad cols 80..95: col 80 = 1.0 (bo slot), rest 0 (r13-proven join)
    {
      int prow = wrow + lhi*4 + (llo & 3);
      int cj   = llo >> 2;
      WaL[prow][80 + cj*4 + 0] = (cj == 0) ? (unsigned short)0x3F80 : (unsigned short)0;
      WaL[prow][80 + cj*4 + 1] = 0;
      WaL[prow][80 + cj*4 + 2] = 0;
      WaL[prow][80 + cj*4 + 3] = 0;
    }
  }
  __syncthreads();   // BAR1: WaL + all Xbf staging visible block-wide

  // ---- phases 3+4, per 32-row half (bo via WaL col 80) ----
  const int rg = wave >> 1;
  const int cs = wave & 1;
  #pragma unroll
  for (int ha = 0; ha < 2; ++ha) {
    const int hrow = ha * 32;              // local row base of this half
    f32x4 oacc[16];
    #pragma unroll
    for (int i = 0; i < 16; ++i) oacc[i] = (f32x4){0.f,0.f,0.f,0.f};
    #pragma unroll
    for (int ks = 0; ks < 3; ++ks) {
      bf16x8 a = *(const bf16x8*)&WaL[hrow + rg*16 + llo][ks*32 + lhi*8];
      #pragma unroll
      for (int tile = 0; tile < 16; ++tile) {
        int ntile = cs*16 + tile;
        bf16x8 b = *(const bf16x8*)(Utf + (size_t)(ntile*3 + ks)*512 + lane*8);
        oacc[tile] = __builtin_amdgcn_mfma_f32_16x16x32_bf16(a, b, oacc[tile], 0, 0, 0);
      }
    }
    // oacc[tile][r] = (attn+bo)[local m = hrow+rg*16+lhi*4+r][n = cs*256+tile*16+llo]

    // epilogue: +x residual (LDS bf16), LN stats, store
    float s[4] = {0,0,0,0}, q[4] = {0,0,0,0};
    #pragma unroll
    for (int tile = 0; tile < 16; ++tile) {
      int n = cs*256 + tile*16 + llo;
      #pragma unroll
      for (int r = 0; r < 4; ++r) {
        int m = hrow + rg*16 + lhi*4 + r;
        float xres = bf2f(*(const unsigned short*)
            ((const char*)Xbf + m*1024 + ((n*2) ^ ((m & 7) << 4))));
        float val = oacc[tile][r] + xres;
        oacc[tile][r] = val;
        s[r] += val;
        q[r] = fmaf(val, val, q[r]);
      }
    }
    #pragma unroll
    for (int r = 0; r < 4; ++r) {
      #pragma unroll
      for (int off = 1; off < 16; off <<= 1) {
        s[r] += __shfl_xor(s[r], off, 64);
        q[r] += __shfl_xor(q[r], off, 64);
      }
    }
    if (llo == 0) {
      #pragma unroll
      for (int r = 0; r < 4; ++r) {
        rs_[hrow + rg*16 + lhi*4 + r][cs] = s[r];
        rq_[hrow + rg*16 + lhi*4 + r][cs] = q[r];
      }
    }
    __syncthreads();   // BAR2 / BAR3: stats for this half ready
    float mu_r[4], rstd_r[4];
    #pragma unroll
    for (int r = 0; r < 4; ++r) {
      int m = hrow + rg*16 + lhi*4 + r;
      float sum = rs_[m][0] + rs_[m][1];
      float sq  = rq_[m][0] + rq_[m][1];
      float mu  = sum * (1.f/(float)D_);
      float var = sq * (1.f/(float)D_) - mu*mu;
      mu_r[r]   = mu;
      rstd_r[r] = rsqrtf(var + 1e-5f);
    }
    #pragma unroll
    for (int tile = 0; tile < 16; ++tile) {
      int n = cs*256 + tile*16 + llo;
      float g = gamma[n], bt = beta[n];
      #pragma unroll
      for (int r = 0; r < 4; ++r) {
        int m = hrow + rg*16 + lhi*4 + r;
        out[(size_t)(row0 + m)*D_ + n] = (oacc[tile][r] - mu_r[r]) * rstd_r[r] * g + bt;
      }
    }
  }
}

extern "C" void kernel_launch(void* const* d_in, const int* in_sizes, int n_in,
                              void* d_out, int out_size, void* d_ws, size_t ws_size,
                              hipStream_t stream) {
  const float* x     = (const float*)d_in[0];
  const float* ce    = (const float*)d_in[1];
  const float* Wq    = (const float*)d_in[2];
  const float* bq    = (const float*)d_in[3];
  const float* Wk    = (const float*)d_in[4];
  const float* bk    = (const float*)d_in[5];
  const float* Wv    = (const float*)d_in[6];
  const float* bv    = (const float*)d_in[7];
  const float* Wo    = (const float*)d_in[8];
  const float* bo    = (const float*)d_in[9];
  const float* gamma = (const float*)d_in[10];
  const float* beta  = (const float*)d_in[11];
  float* out = (float*)d_out;

  char* ws = (char*)d_ws;
  unsigned short* Mtf = (unsigned short*)(ws);           // 80*512*2 = 81920
  unsigned short* Utf = (unsigned short*)(ws + 81920);   // 512*96*2 = 98304
  float* s0g          = (float*)(ws + 180224);           // 320

  prep<<<CHP_, 512, 0, stream>>>(ce, Wq, bq, Wk, bk, Wv, bv, Wo, bo,
                                 Mtf, Utf, s0g);
  fused64<<<NROW/64, 256, 0, stream>>>(x, Mtf, Utf, s0g, gamma, beta, out);
}

// Round 21
// 123.024 us; speedup vs baseline: 1.1831x; 1.0648x over previous
//
#include <hip/hip_runtime.h>
#include <hip/hip_bf16.h>

#define C_  19
#define D_  512
#define H_  4
#define DH_ 128
#define NROW 65536
#define CHP_ 96

typedef float f32x4 __attribute__((ext_vector_type(4)));
typedef short bf16x8 __attribute__((ext_vector_type(8)));

__device__ __forceinline__ unsigned short f2bf(float f) {
  union { __hip_bfloat16 h; unsigned short s; } u;
  u.h = __float2bfloat16(f);
  return u.s;
}
__device__ __forceinline__ float bf2f(unsigned short h) {
  return __uint_as_float(((unsigned int)h) << 16);
}
__device__ __forceinline__ bf16x8 ld_cvt8(const float* p) {
  f32x4 v0 = *(const f32x4*)p;
  f32x4 v1 = *(const f32x4*)(p + 4);
  bf16x8 a;
  a[0]=(short)f2bf(v0[0]); a[1]=(short)f2bf(v0[1]);
  a[2]=(short)f2bf(v0[2]); a[3]=(short)f2bf(v0[3]);
  a[4]=(short)f2bf(v1[0]); a[5]=(short)f2bf(v1[1]);
  a[6]=(short)f2bf(v1[2]); a[7]=(short)f2bf(v1[3]);
  return a;
}
__device__ __forceinline__ float dot4(f32x4 a, f32x4 b, float acc) {
  return fmaf(a[0],b[0], fmaf(a[1],b[1], fmaf(a[2],b[2], fmaf(a[3],b[3], acc))));
}

// ---- prep: layouts r17-verbatim; dots vectorized + 4-way accs -------------
__global__ __launch_bounds__(512) void prep(
    const float* __restrict__ ce,
    const float* __restrict__ Wq, const float* __restrict__ bq,
    const float* __restrict__ Wk, const float* __restrict__ bk,
    const float* __restrict__ Wv, const float* __restrict__ bv,
    const float* __restrict__ Wo, const float* __restrict__ bo,
    unsigned short* __restrict__ Mtf, unsigned short* __restrict__ Utf,
    float* __restrict__ s0g)
{
  __shared__ __attribute__((aligned(16))) float KV[2][DH_];
  __shared__ float KVp[512];

  const int p = blockIdx.x;   // 0..95
  const int m = threadIdx.x;  // 0..511
  const int mt_off = (p>>4)*8192 + (m>>5)*512 + ((((m>>3)&3)<<4) + (p&15))*8 + (m&7);
  const int ut_off = ((m>>4)*3 + (p>>5))*512 + ((((p>>3)&3)<<4) + (m&15))*8 + (p&7);
  const int c = p >> 2, h = p & 3;

  if (c >= C_) {   // dead slots; p==80 carries bo (Wa col 80 is 1.0)
    if (p < 80) { Mtf[mt_off] = 0; if (m == 0) s0g[p] = 0.f; }
    Utf[ut_off] = (p == 80) ? f2bf(bo[m]) : (unsigned short)0;
    return;
  }

  // K/V half-dots: f32x4 loads (bases 1KB-aligned), 4 accumulators
  {
    const int which = m >> 8;            // 0:K 1:V
    const int dh    = (m >> 1) & 127;
    const int half  = m & 1;
    const float* w = (which ? Wv : Wk) + (size_t)(h*DH_ + dh)*D_ + half*256;
    const float* e = ce + (size_t)c*D_ + half*256;
    float a0 = 0.f, a1 = 0.f, a2 = 0.f, a3 = 0.f;
    #pragma unroll
    for (int d = 0; d < 256; d += 16) {
      a0 = dot4(*(const f32x4*)(w+d   ), *(const f32x4*)(e+d   ), a0);
      a1 = dot4(*(const f32x4*)(w+d+4 ), *(const f32x4*)(e+d+4 ), a1);
      a2 = dot4(*(const f32x4*)(w+d+8 ), *(const f32x4*)(e+d+8 ), a2);
      a3 = dot4(*(const f32x4*)(w+d+12), *(const f32x4*)(e+d+12), a3);
    }
    KVp[m] = (a0 + a1) + (a2 + a3);
  }
  __syncthreads();
  if (m < 256) {
    const int which = m >> 7, dh = m & 127;
    KV[which][dh] = KVp[2*m] + KVp[2*m+1] + (which ? bv : bk)[h*DH_ + dh];
  }
  __syncthreads();

  const float rs128 = 0.08838834764831843f;  // 1/sqrt(128)

  // Mtf: column reads (coalesced across lanes), 4 accumulators
  {
    float m0 = 0.f, m1 = 0.f, m2 = 0.f, m3 = 0.f;
    const float* wq = Wq + (size_t)(h*DH_)*D_ + m;
    #pragma unroll 8
    for (int dh = 0; dh < DH_; dh += 4) {
      m0 = fmaf(wq[(size_t)(dh  )*D_], KV[0][dh  ], m0);
      m1 = fmaf(wq[(size_t)(dh+1)*D_], KV[0][dh+1], m1);
      m2 = fmaf(wq[(size_t)(dh+2)*D_], KV[0][dh+2], m2);
      m3 = fmaf(wq[(size_t)(dh+3)*D_], KV[0][dh+3], m3);
    }
    Mtf[mt_off] = f2bf(((m0 + m1) + (m2 + m3)) * rs128);
  }

  // Utf: per-thread contiguous row reads, f32x4 + 4 accumulators
  {
    const float* wor = Wo + (size_t)m*D_ + h*DH_;
    float u0 = 0.f, u1 = 0.f, u2 = 0.f, u3 = 0.f;
    #pragma unroll
    for (int dh = 0; dh < DH_; dh += 16) {
      u0 = dot4(*(const f32x4*)(wor+dh   ), *(const f32x4*)(&KV[1][dh   ]), u0);
      u1 = dot4(*(const f32x4*)(wor+dh+4 ), *(const f32x4*)(&KV[1][dh+4 ]), u1);
      u2 = dot4(*(const f32x4*)(wor+dh+8 ), *(const f32x4*)(&KV[1][dh+8 ]), u2);
      u3 = dot4(*(const f32x4*)(wor+dh+12), *(const f32x4*)(&KV[1][dh+12]), u3);
    }
    Utf[ut_off] = f2bf((u0 + u1) + (u2 + u3));
  }

  if (m == 0) {
    float sa = 0.f;
    for (int dh = 0; dh < DH_; ++dh) sa = fmaf(bq[h*DH_+dh], KV[0][dh], sa);
    s0g[p] = sa * rs128;
  }
}

// ---- fused64 (r17/r20-verbatim): 64 rows/block, 4 waves, 3 barriers -------
__global__ __launch_bounds__(256) void fused64(
    const float* __restrict__ x,
    const unsigned short* __restrict__ Mtf,  // frag-ordered [5][16][64][8]
    const unsigned short* __restrict__ Utf,  // frag-ordered [32][3][64][8]
    const float* __restrict__ s0g,           // [80] permuted
    const float* __restrict__ gamma, const float* __restrict__ beta,
    float* __restrict__ out)
{
  __shared__ __attribute__((aligned(16))) unsigned short Xbf[64*512]; // 64KB swizzled
  __shared__ __attribute__((aligned(16))) unsigned short WaL[64][104];
  __shared__ float rs_[64][2], rq_[64][2];

  const int t    = threadIdx.x;
  const int wave = t >> 6;
  const int lane = t & 63;
  const int lhi  = lane >> 4;
  const int llo  = lane & 15;
  const int row0 = blockIdx.x * 64;
  const int wrow = wave * 16;     // this wave's local row base

  // ---- phase 0: stage this wave's 16 rows -> Xbf (bf16, swizzled) ----
  {
    #pragma unroll
    for (int j = 0; j < 16; ++j) {
      bf16x8 a = ld_cvt8(x + (size_t)(row0 + wrow + j)*D_ + lane*8);
      int byteoff = (wrow + j)*1024 + ((lane*16) ^ ((j & 7) << 4));
      *(bf16x8*)((char*)Xbf + byteoff) = a;
    }
  }
  // wave-local fence: this wave's LDS writes -> this wave's phase-1 reads
  asm volatile("s_waitcnt lgkmcnt(0)" ::: "memory");
  __builtin_amdgcn_sched_barrier(0);

  // ---- phase 1: S-GEMM, ks-outer, 5 accs, A from LDS ----
  {
    const char* xb = (const char*)Xbf + (wrow + llo)*1024;
    const int swz = (llo & 7) << 4;
    f32x4 acc0 = (f32x4){0,0,0,0}, acc1 = acc0, acc2 = acc0, acc3 = acc0, acc4 = acc0;
    #pragma unroll
    for (int ks = 0; ks < 16; ++ks) {
      bf16x8 a = *(const bf16x8*)(xb + ((ks*64 + lhi*16) ^ swz));
      acc0 = __builtin_amdgcn_mfma_f32_16x16x32_bf16(a, *(const bf16x8*)(Mtf + 0*8192 + ks*512 + lane*8), acc0, 0, 0, 0);
      acc1 = __builtin_amdgcn_mfma_f32_16x16x32_bf16(a, *(const bf16x8*)(Mtf + 1*8192 + ks*512 + lane*8), acc1, 0, 0, 0);
      acc2 = __builtin_amdgcn_mfma_f32_16x16x32_bf16(a, *(const bf16x8*)(Mtf + 2*8192 + ks*512 + lane*8), acc2, 0, 0, 0);
      acc3 = __builtin_amdgcn_mfma_f32_16x16x32_bf16(a, *(const bf16x8*)(Mtf + 3*8192 + ks*512 + lane*8), acc3, 0, 0, 0);
      acc4 = __builtin_amdgcn_mfma_f32_16x16x32_bf16(a, *(const bf16x8*)(Mtf + 4*8192 + ks*512 + lane*8), acc4, 0, 0, 0);
    }
    // in-register softmax over p (h = llo&3 lane-invariant under xor 4,8)
    const bool dead = (llo >= 12);   // slot p=64+llo: c = 16+(llo>>2) == 19
    float s0v0 = s0g[llo], s0v1 = s0g[16+llo], s0v2 = s0g[32+llo],
          s0v3 = s0g[48+llo], s0v4 = s0g[64+llo];
    #pragma unroll
    for (int r = 0; r < 4; ++r) {
      float v0 = acc0[r] + s0v0;
      float v1 = acc1[r] + s0v1;
      float v2 = acc2[r] + s0v2;
      float v3 = acc3[r] + s0v3;
      float v4 = dead ? -1e30f : (acc4[r] + s0v4);
      float mx = fmaxf(fmaxf(fmaxf(v0, v1), fmaxf(v2, v3)), v4);
      mx = fmaxf(mx, __shfl_xor(mx, 4, 64));
      mx = fmaxf(mx, __shfl_xor(mx, 8, 64));
      float e0 = __expf(v0 - mx), e1 = __expf(v1 - mx), e2 = __expf(v2 - mx),
            e3 = __expf(v3 - mx), e4 = dead ? 0.f : __expf(v4 - mx);
      float sm = e0 + e1 + e2 + e3 + e4;
      sm += __shfl_xor(sm, 4, 64);
      sm += __shfl_xor(sm, 8, 64);
      float inv = 1.f / sm;
      int lr = wrow + lhi*4 + r;
      WaL[lr][     llo] = f2bf(e0 * inv);
      WaL[lr][16 + llo] = f2bf(e1 * inv);
      WaL[lr][32 + llo] = f2bf(e2 * inv);
      WaL[lr][48 + llo] = f2bf(e3 * inv);
      WaL[lr][64 + llo] = f2bf(e4 * inv);
    }
    // pad cols 80..95: col 80 = 1.0 (bo slot), rest 0 (r13-proven join)
    {
      int prow = wrow + lhi*4 + (llo & 3);
      int cj   = llo >> 2;
      WaL[prow][80 + cj*4 + 0] = (cj == 0) ? (unsigned short)0x3F80 : (unsigned short)0;
      WaL[prow][80 + cj*4 + 1] = 0;
      WaL[prow][80 + cj*4 + 2] = 0;
      WaL[prow][80 + cj*4 + 3] = 0;
    }
  }
  __syncthreads();   // BAR1: WaL + all Xbf staging visible block-wide

  // ---- phases 3+4, per 32-row half (bo via WaL col 80) ----
  const int rg = wave >> 1;
  const int cs = wave & 1;
  #pragma unroll
  for (int ha = 0; ha < 2; ++ha) {
    const int hrow = ha * 32;              // local row base of this half
    f32x4 oacc[16];
    #pragma unroll
    for (int i = 0; i < 16; ++i) oacc[i] = (f32x4){0.f,0.f,0.f,0.f};
    #pragma unroll
    for (int ks = 0; ks < 3; ++ks) {
      bf16x8 a = *(const bf16x8*)&WaL[hrow + rg*16 + llo][ks*32 + lhi*8];
      #pragma unroll
      for (int tile = 0; tile < 16; ++tile) {
        int ntile = cs*16 + tile;
        bf16x8 b = *(const bf16x8*)(Utf + (size_t)(ntile*3 + ks)*512 + lane*8);
        oacc[tile] = __builtin_amdgcn_mfma_f32_16x16x32_bf16(a, b, oacc[tile], 0, 0, 0);
      }
    }
    // oacc[tile][r] = (attn+bo)[local m = hrow+rg*16+lhi*4+r][n = cs*256+tile*16+llo]

    // epilogue: +x residual (LDS bf16), LN stats, store
    float s[4] = {0,0,0,0}, q[4] = {0,0,0,0};
    #pragma unroll
    for (int tile = 0; tile < 16; ++tile) {
      int n = cs*256 + tile*16 + llo;
      #pragma unroll
      for (int r = 0; r < 4; ++r) {
        int m = hrow + rg*16 + lhi*4 + r;
        float xres = bf2f(*(const unsigned short*)
            ((const char*)Xbf + m*1024 + ((n*2) ^ ((m & 7) << 4))));
        float val = oacc[tile][r] + xres;
        oacc[tile][r] = val;
        s[r] += val;
        q[r] = fmaf(val, val, q[r]);
      }
    }
    #pragma unroll
    for (int r = 0; r < 4; ++r) {
      #pragma unroll
      for (int off = 1; off < 16; off <<= 1) {
        s[r] += __shfl_xor(s[r], off, 64);
        q[r] += __shfl_xor(q[r], off, 64);
      }
    }
    if (llo == 0) {
      #pragma unroll
      for (int r = 0; r < 4; ++r) {
        rs_[hrow + rg*16 + lhi*4 + r][cs] = s[r];
        rq_[hrow + rg*16 + lhi*4 + r][cs] = q[r];
      }
    }
    __syncthreads();   // BAR2 / BAR3: stats for this half ready
    float mu_r[4], rstd_r[4];
    #pragma unroll
    for (int r = 0; r < 4; ++r) {
      int m = hrow + rg*16 + lhi*4 + r;
      float sum = rs_[m][0] + rs_[m][1];
      float sq  = rq_[m][0] + rq_[m][1];
      float mu  = sum * (1.f/(float)D_);
      float var = sq * (1.f/(float)D_) - mu*mu;
      mu_r[r]   = mu;
      rstd_r[r] = rsqrtf(var + 1e-5f);
    }
    #pragma unroll
    for (int tile = 0; tile < 16; ++tile) {
      int n = cs*256 + tile*16 + llo;
      float g = gamma[n], bt = beta[n];
      #pragma unroll
      for (int r = 0; r < 4; ++r) {
        int m = hrow + rg*16 + lhi*4 + r;
        out[(size_t)(row0 + m)*D_ + n] = (oacc[tile][r] - mu_r[r]) * rstd_r[r] * g + bt;
      }
    }
  }
}

extern "C" void kernel_launch(void* const* d_in, const int* in_sizes, int n_in,
                              void* d_out, int out_size, void* d_ws, size_t ws_size,
                              hipStream_t stream) {
  const float* x     = (const float*)d_in[0];
  const float* ce    = (const float*)d_in[1];
  const float* Wq    = (const float*)d_in[2];
  const float* bq    = (const float*)d_in[3];
  const float* Wk    = (const float*)d_in[4];
  const float* bk    = (const float*)d_in[5];
  const float* Wv    = (const float*)d_in[6];
  const float* bv    = (const float*)d_in[7];
  const float* Wo    = (const float*)d_in[8];
  const float* bo    = (const float*)d_in[9];
  const float* gamma = (const float*)d_in[10];
  const float* beta  = (const float*)d_in[11];
  float* out = (float*)d_out;

  char* ws = (char*)d_ws;
  unsigned short* Mtf = (unsigned short*)(ws);           // 80*512*2 = 81920
  unsigned short* Utf = (unsigned short*)(ws + 81920);   // 512*96*2 = 98304
  float* s0g          = (float*)(ws + 180224);           // 320

  prep<<<CHP_, 512, 0, stream>>>(ce, Wq, bq, Wk, bk, Wv, bv, Wo, bo,
                                 Mtf, Utf, s0g);
  fused64<<<NROW/64, 256, 0, stream>>>(x, Mtf, Utf, s0g, gamma, beta, out);
}